// Round 7
// baseline (165.957 us; speedup 1.0000x reference)
//
#include <hip/hip_runtime.h>
#include <math.h>

#define BATCH 16
#define CH 256
#define NG 8
#define NH 4
#define HD 64
#define NN 1024
#define GSZ 32
#define GELEMS (GSZ * NN)

typedef __attribute__((ext_vector_type(8))) __bf16 bf16x8;
typedef __attribute__((ext_vector_type(4))) __bf16 bf16x4;
typedef __attribute__((ext_vector_type(4))) _Float16 f16x4;
typedef __attribute__((ext_vector_type(4))) float f32x4;

__device__ __forceinline__ unsigned short f2b(float f) {
    union { __bf16 h; unsigned short u; } c; c.h = (__bf16)f; return c.u;
}
__device__ __forceinline__ unsigned short f2h(float f) {
    union { _Float16 h; unsigned short u; } c; c.h = (_Float16)f; return c.u;
}

#define MFMA(a, b, c) __builtin_amdgcn_mfma_f32_16x16x32_bf16(a, b, c, 0, 0, 0)
#define MFMA16(a, b, c) __builtin_amdgcn_mfma_f32_16x16x16f16(a, b, c, 0, 0, 0)

// ---- prep: blocks 0..127 = GN stats per (b,g); blocks 128..255 = W fp32->bf16 ----
__global__ __launch_bounds__(256) void prep_kernel(
    const float* __restrict__ x, const float* __restrict__ qkv_w,
    const float* __restrict__ proj_w, float* __restrict__ stats,
    unsigned short* __restrict__ wq, unsigned short* __restrict__ wp)
{
    int tid = threadIdx.x;
    if (blockIdx.x >= 128) {
        int t = (blockIdx.x - 128) * 256 + tid;
        const float* src; unsigned short* dst; size_t off;
        if (t < 24576) { src = qkv_w; dst = wq; off = (size_t)t * 8; }
        else           { src = proj_w; dst = wp; off = (size_t)(t - 24576) * 8; }
        const float4* s4 = (const float4*)(src + off);
        float4 a = s4[0], b = s4[1];
        bf16x8 pk;
        pk[0] = (__bf16)a.x; pk[1] = (__bf16)a.y; pk[2] = (__bf16)a.z; pk[3] = (__bf16)a.w;
        pk[4] = (__bf16)b.x; pk[5] = (__bf16)b.y; pk[6] = (__bf16)b.z; pk[7] = (__bf16)b.w;
        *(bf16x8*)(dst + off) = pk;
        return;
    }
    int b = blockIdx.x >> 3, g = blockIdx.x & 7;
    const float4* x4 = (const float4*)(x + ((size_t)b * CH + g * GSZ) * NN);
    float s = 0.f, ss = 0.f;
    #pragma unroll
    for (int i = 0; i < 32; ++i) {
        float4 v = x4[tid + i * 256];
        s  += v.x + v.y + v.z + v.w;
        ss += v.x * v.x + v.y * v.y + v.z * v.z + v.w * v.w;
    }
    #pragma unroll
    for (int off = 1; off < 64; off <<= 1) {
        s  += __shfl_xor(s, off);
        ss += __shfl_xor(ss, off);
    }
    __shared__ float red[8];
    int wave = tid >> 6, lane = tid & 63;
    if (lane == 0) { red[wave] = s; red[4 + wave] = ss; }
    __syncthreads();
    if (tid == 0) {
        float ts  = red[0] + red[1] + red[2] + red[3];
        float tss = red[4] + red[5] + red[6] + red[7];
        float mu  = ts * (1.f / GELEMS);
        float var = tss * (1.f / GELEMS) - mu * mu;
        stats[blockIdx.x * 2] = mu;
        stats[blockIdx.x * 2 + 1] = rsqrtf(var + 1e-5f);
    }
}

// ---- GN apply + transpose: block=(n-tile 64, b). x[b][c][n] -> hT[b][n][c] bf16 ----
__global__ __launch_bounds__(256) void gn_apply_kernel(
    const float* __restrict__ x, const float* __restrict__ w,
    const float* __restrict__ bb, const float* __restrict__ stats,
    unsigned short* __restrict__ hT)
{
    __shared__ float Ts[64][68];
    __shared__ float wcp[256], bcp[256];
    const int b = blockIdx.y, n0 = blockIdx.x * 64;
    const int tid = threadIdx.x;
    {
        int c = tid, g = c >> 5;
        float mu = stats[(b * 8 + g) * 2], rs = stats[(b * 8 + g) * 2 + 1];
        float wc = w[c] * rs;
        wcp[c] = wc; bcp[c] = bb[c] - mu * wc;
    }
    __syncthreads();
    const float* xb = x + (size_t)b * CH * NN;
    const int c_l = tid >> 2, nq = tid & 3;
    const int n_l = tid >> 2, cq = tid & 3;
    for (int cb = 0; cb < 4; ++cb) {
        #pragma unroll
        for (int i = 0; i < 4; ++i)
            *(float4*)&Ts[c_l][nq * 4 + i * 16] =
                *(const float4*)(xb + (size_t)(cb * 64 + c_l) * NN + n0 + nq * 4 + i * 16);
        __syncthreads();
        #pragma unroll
        for (int s = 0; s < 2; ++s) {
            int cbase = cq * 16 + s * 8;
            bf16x8 pk;
            #pragma unroll
            for (int j = 0; j < 8; ++j) {
                int c = cb * 64 + cbase + j;
                pk[j] = (__bf16)(Ts[cbase + j][n_l] * wcp[c] + bcp[c]);
            }
            *(bf16x8*)(hT + ((size_t)b * NN + n0 + n_l) * CH + cb * 64 + cbase) = pk;
        }
        __syncthreads();
    }
}

// ---- GEMM v2: 128x128 block tile, 4 waves (2x2), 64x64/wave, 4x4 micro-tile. ----
// BK=64, XOR-swizzled unpadded LDS rows (2-way = free). 8 frag reads : 16 MFMA.
// KIND 0: qkv. y<4 -> q/k, D[n][o] -> qkvT bf16; y in {4,5} -> v, D[o][n] -> vbuf f16.
// KIND 1: proj. D[o][n] -> fp32 out + bias + residual.
template <int KIND>
__global__ __launch_bounds__(256) void gemm_kernel(
    const unsigned short* __restrict__ AT,   // [b][1024][256] bf16
    const unsigned short* __restrict__ Wb,   // [Mtot][256] bf16
    const float* __restrict__ bias,
    unsigned short* __restrict__ outT, unsigned short* __restrict__ outV,
    const float* __restrict__ res, float* __restrict__ out)
{
    __shared__ __align__(16) unsigned short Hs[128 * 64];   // A tile: rows n, 64 k
    __shared__ __align__(16) unsigned short Wl[128 * 64];   // B tile: rows o, 64 k
    const int b = blockIdx.z, o0 = blockIdx.y * 128, n0 = blockIdx.x * 128;
    const int tid = threadIdx.x;
    const int lane = tid & 63, w = tid >> 6;
    const int l = lane & 15, quad = lane >> 4;
    const int iw = w & 1, jw = w >> 1;           // n-half, o-half (64 each)
    const bool qk_mode = (KIND == 0) && (blockIdx.y < 4);
    const int sr = tid >> 3, sc = tid & 7;       // staging: rows 0..31(+32i), chunk 0..7

    f32x4 acc[4][4] = {};
    for (int cc = 0; cc < 4; ++cc) {
        const int cc0 = cc * 64;
        #pragma unroll
        for (int i = 0; i < 4; ++i) {
            int r = sr + i * 32;
            int p = (sc ^ (r & 7)) * 8;
            *(bf16x8*)&Hs[r * 64 + p] =
                *(const bf16x8*)(AT + ((size_t)b * NN + n0 + r) * CH + cc0 + sc * 8);
            *(bf16x8*)&Wl[r * 64 + p] =
                *(const bf16x8*)(Wb + (size_t)(o0 + r) * CH + cc0 + sc * 8);
        }
        __syncthreads();
        #pragma unroll
        for (int kt = 0; kt < 2; ++kt) {
            const int q = ((kt * 4 + quad) ^ (l & 7)) * 8;
            bf16x8 hf[4], wf[4];
            #pragma unroll
            for (int i = 0; i < 4; ++i)
                hf[i] = *(const bf16x8*)&Hs[(iw * 64 + i * 16 + l) * 64 + q];
            #pragma unroll
            for (int j = 0; j < 4; ++j)
                wf[j] = *(const bf16x8*)&Wl[(jw * 64 + j * 16 + l) * 64 + q];
            #pragma unroll
            for (int i = 0; i < 4; ++i)
                #pragma unroll
                for (int j = 0; j < 4; ++j)
                    acc[i][j] = qk_mode ? MFMA(hf[i], wf[j], acc[i][j])
                                        : MFMA(wf[j], hf[i], acc[i][j]);
        }
        __syncthreads();
    }

    #pragma unroll
    for (int i = 0; i < 4; ++i)
        #pragma unroll
        for (int j = 0; j < 4; ++j) {
            if (qk_mode) {
                // D[n][o]: row = n (quad*4+r), col = o (l)
                int o = o0 + jw * 64 + j * 16 + l;
                float bs = bias[o];
                #pragma unroll
                for (int r = 0; r < 4; ++r) {
                    int n = n0 + iw * 64 + i * 16 + quad * 4 + r;
                    outT[((size_t)b * NN + n) * 512 + o] = f2b(acc[i][j][r] + bs);
                }
            } else {
                // D[o][n]: row = o (quad*4+r), col = n (l)
                int o = o0 + jw * 64 + j * 16 + quad * 4;
                int n = n0 + iw * 64 + i * 16 + l;
                #pragma unroll
                for (int r = 0; r < 4; ++r) {
                    float v = acc[i][j][r] + bias[o + r];
                    if (KIND == 0)
                        outV[((size_t)b * CH + (o + r - 512)) * NN + n] = f2h(v);  // f16
                    else {
                        size_t idx = ((size_t)b * CH + o + r) * NN + n;
                        out[idx] = v + res[idx];
                    }
                }
            }
        }
}

// ---- Flash attention v4 (R6-proven): LDS dbuf K/V swizzled, P in registers ----
__global__ __launch_bounds__(256, 3) void attn_kernel(
    const unsigned short* __restrict__ qkvT,   // [b][n][512] bf16 (q 0..255, k 256..511)
    const unsigned short* __restrict__ vbuf,   // [b][256][1024] f16
    unsigned short* __restrict__ ctxT)         // [b][n][256] bf16
{
    __shared__ __align__(16) unsigned short KV[2][8192];
    __shared__ float Lred[2][32];
    const int id = blockIdx.x;
    const int bh = id & 63, nt = id >> 6;
    const int b = bh >> 2, hh = bh & 3;
    const int n0 = nt * 64;
    const int tid = threadIdx.x;
    const int lane = tid & 63, w = tid >> 6;
    const int l = lane & 15, quad = lane >> 4;
    const int qx = w & 1, ky = w >> 1;
    const float KL2E = 0.125f * 1.44269504f;
    const int r4 = tid >> 2, c4 = tid & 3;

    bf16x8 qf[2][2];
    {
        const unsigned short* qp = qkvT + ((size_t)b * NN + n0 + 32 * qx + l) * 512 + hh * 64;
        #pragma unroll
        for (int ns = 0; ns < 2; ++ns)
            #pragma unroll
            for (int kt = 0; kt < 2; ++kt)
                qf[ns][kt] = *(const bf16x8*)(qp + (size_t)ns * 16 * 512 + kt * 32 + quad * 8);
    }

    const unsigned short* gk = qkvT + ((size_t)b * NN + r4) * 512 + 256 + hh * 64;
    const unsigned short* gv = vbuf + ((size_t)b * CH + hh * 64 + r4) * NN;
    const int p0 = (c4 ^ (r4 & 7)) * 8, p1 = ((c4 + 4) ^ (r4 & 7)) * 8;

    bf16x8 kpre0, kpre1, vpre0, vpre1;
    kpre0 = *(const bf16x8*)(gk + c4 * 8);
    kpre1 = *(const bf16x8*)(gk + (c4 + 4) * 8);
    vpre0 = *(const bf16x8*)(gv + c4 * 8);
    vpre1 = *(const bf16x8*)(gv + (c4 + 4) * 8);
    *(bf16x8*)&KV[0][r4 * 64 + p0] = kpre0;
    *(bf16x8*)&KV[0][r4 * 64 + p1] = kpre1;
    *(bf16x8*)&KV[0][4096 + r4 * 64 + p0] = vpre0;
    *(bf16x8*)&KV[0][4096 + r4 * 64 + p1] = vpre1;
    __syncthreads();

    float l_w[2] = {0.f, 0.f};
    f32x4 oacc[2][4] = {};

    for (int mt = 0; mt < 16; ++mt) {
        const int cur = mt & 1;
        if (mt < 15) {
            const unsigned short* gk1 = gk + (size_t)(mt + 1) * 64 * 512;
            const unsigned short* gv1 = gv + (mt + 1) * 64;
            kpre0 = *(const bf16x8*)(gk1 + c4 * 8);
            kpre1 = *(const bf16x8*)(gk1 + (c4 + 4) * 8);
            vpre0 = *(const bf16x8*)(gv1 + c4 * 8);
            vpre1 = *(const bf16x8*)(gv1 + (c4 + 4) * 8);
        }

        bf16x8 kf[2][2];
        #pragma unroll
        for (int mt2 = 0; mt2 < 2; ++mt2)
            #pragma unroll
            for (int kt = 0; kt < 2; ++kt)
                kf[mt2][kt] = *(const bf16x8*)
                    &KV[cur][(32 * ky + 16 * mt2 + l) * 64 + (((kt * 4 + quad) ^ (l & 7)) * 8)];

        f32x4 sacc[2][2] = {};
        #pragma unroll
        for (int kt = 0; kt < 2; ++kt)
            #pragma unroll
            for (int mt2 = 0; mt2 < 2; ++mt2)
                #pragma unroll
                for (int ns = 0; ns < 2; ++ns)
                    sacc[mt2][ns] = MFMA(kf[mt2][kt], qf[ns][kt], sacc[mt2][ns]);

        f16x4 pf[2][2];
        #pragma unroll
        for (int mt2 = 0; mt2 < 2; ++mt2)
            #pragma unroll
            for (int ns = 0; ns < 2; ++ns)
                #pragma unroll
                for (int r = 0; r < 4; ++r) {
                    float p = exp2f(sacc[mt2][ns][r] * KL2E);
                    l_w[ns] += p;
                    pf[mt2][ns][r] = (_Float16)p;
                }

        #pragma unroll
        for (int mt2 = 0; mt2 < 2; ++mt2) {
            const int q8 = 4 * ky + 2 * mt2 + (quad >> 1);
            const int vo = ((q8 ^ (l & 7)) * 8) + (quad & 1) * 4;
            #pragma unroll
            for (int ct = 0; ct < 4; ++ct) {
                f16x4 va = *(const f16x4*)&KV[cur][4096 + (16 * ct + l) * 64 + vo];
                #pragma unroll
                for (int ns = 0; ns < 2; ++ns)
                    oacc[ns][ct] = MFMA16(va, pf[mt2][ns], oacc[ns][ct]);
            }
        }

        if (mt < 15) {
            const int nxt = cur ^ 1;
            *(bf16x8*)&KV[nxt][r4 * 64 + p0] = kpre0;
            *(bf16x8*)&KV[nxt][r4 * 64 + p1] = kpre1;
            *(bf16x8*)&KV[nxt][4096 + r4 * 64 + p0] = vpre0;
            *(bf16x8*)&KV[nxt][4096 + r4 * 64 + p1] = vpre1;
            __syncthreads();
        }
    }

    #pragma unroll
    for (int ns = 0; ns < 2; ++ns) {
        l_w[ns] += __shfl_xor(l_w[ns], 16);
        l_w[ns] += __shfl_xor(l_w[ns], 32);
    }
    float* Ored = (float*)&KV[0][0];
    if (ky == 1) {
        #pragma unroll
        for (int ns = 0; ns < 2; ++ns) {
            if (quad == 0) Lred[qx][ns * 16 + l] = l_w[ns];
            #pragma unroll
            for (int ct = 0; ct < 4; ++ct)
                #pragma unroll
                for (int r = 0; r < 4; ++r)
                    Ored[qx * 2048 + (16 * ct + quad * 4 + r) * 32 + ns * 16 + l] =
                        oacc[ns][ct][r];
        }
    }
    __syncthreads();
    if (ky == 0) {
        unsigned short* cb = ctxT + ((size_t)b * NN + n0 + 32 * qx) * CH + hh * 64;
        #pragma unroll
        for (int ns = 0; ns < 2; ++ns) {
            float inv = 1.f / (l_w[ns] + Lred[qx][ns * 16 + l]);
            #pragma unroll
            for (int ct = 0; ct < 4; ++ct) {
                bf16x4 pk;
                #pragma unroll
                for (int r = 0; r < 4; ++r)
                    pk[r] = (__bf16)((oacc[ns][ct][r] +
                             Ored[qx * 2048 + (16 * ct + quad * 4 + r) * 32 + ns * 16 + l]) * inv);
                *(bf16x4*)(cb + (size_t)(ns * 16 + l) * CH + 16 * ct + quad * 4) = pk;
            }
        }
    }
}

extern "C" void kernel_launch(void* const* d_in, const int* in_sizes, int n_in,
                              void* d_out, int out_size, void* d_ws, size_t ws_size,
                              hipStream_t stream)
{
    const float* x      = (const float*)d_in[0];
    const float* norm_w = (const float*)d_in[1];
    const float* norm_b = (const float*)d_in[2];
    const float* qkv_w  = (const float*)d_in[3];
    const float* qkv_b  = (const float*)d_in[4];
    const float* proj_w = (const float*)d_in[5];
    const float* proj_b = (const float*)d_in[6];
    float* out = (float*)d_out;

    unsigned short* hT   = (unsigned short*)d_ws;
    unsigned short* qkvT = hT   + (size_t)BATCH * NN * CH;
    unsigned short* vbuf = qkvT + (size_t)BATCH * NN * 512;
    unsigned short* ctxT = vbuf + (size_t)BATCH * CH * NN;
    unsigned short* wq   = ctxT + (size_t)BATCH * NN * CH;
    unsigned short* wp   = wq + (size_t)768 * CH;
    float* stats         = (float*)(wp + (size_t)CH * CH);

    prep_kernel<<<dim3(256), 256, 0, stream>>>(x, qkv_w, proj_w, stats, wq, wp);
    gn_apply_kernel<<<dim3(16, BATCH), 256, 0, stream>>>(x, norm_w, norm_b, stats, hT);
    gemm_kernel<0><<<dim3(8, 6, BATCH), 256, 0, stream>>>(
        hT, wq, qkv_b, qkvT, vbuf, nullptr, nullptr);
    attn_kernel<<<dim3(1024), 256, 0, stream>>>(qkvT, vbuf, ctxT);
    gemm_kernel<1><<<dim3(8, 2, BATCH), 256, 0, stream>>>(
        ctxT, wp, proj_b, nullptr, nullptr, x, out);
}

// Round 8
// 146.641 us; speedup vs baseline: 1.1317x; 1.1317x over previous
//
#include <hip/hip_runtime.h>
#include <math.h>

#define BATCH 16
#define CH 256
#define NG 8
#define NH 4
#define HD 64
#define NN 1024
#define GSZ 32
#define GELEMS (GSZ * NN)

typedef __attribute__((ext_vector_type(8))) __bf16 bf16x8;
typedef __attribute__((ext_vector_type(4))) __bf16 bf16x4;
typedef __attribute__((ext_vector_type(4))) _Float16 f16x4;
typedef __attribute__((ext_vector_type(4))) float f32x4;

__device__ __forceinline__ unsigned short f2b(float f) {
    union { __bf16 h; unsigned short u; } c; c.h = (__bf16)f; return c.u;
}
__device__ __forceinline__ unsigned short f2h(float f) {
    union { _Float16 h; unsigned short u; } c; c.h = (_Float16)f; return c.u;
}

#define MFMA(a, b, c) __builtin_amdgcn_mfma_f32_16x16x32_bf16(a, b, c, 0, 0, 0)
#define MFMA16(a, b, c) __builtin_amdgcn_mfma_f32_16x16x16f16(a, b, c, 0, 0, 0)

// ---- prep: blocks 0..127 = GN stats per (b,g); blocks 128..255 = W fp32->bf16 ----
__global__ __launch_bounds__(256) void prep_kernel(
    const float* __restrict__ x, const float* __restrict__ qkv_w,
    const float* __restrict__ proj_w, float* __restrict__ stats,
    unsigned short* __restrict__ wq, unsigned short* __restrict__ wp)
{
    int tid = threadIdx.x;
    if (blockIdx.x >= 128) {
        int t = (blockIdx.x - 128) * 256 + tid;
        const float* src; unsigned short* dst; size_t off;
        if (t < 24576) { src = qkv_w; dst = wq; off = (size_t)t * 8; }
        else           { src = proj_w; dst = wp; off = (size_t)(t - 24576) * 8; }
        const float4* s4 = (const float4*)(src + off);
        float4 a = s4[0], b = s4[1];
        bf16x8 pk;
        pk[0] = (__bf16)a.x; pk[1] = (__bf16)a.y; pk[2] = (__bf16)a.z; pk[3] = (__bf16)a.w;
        pk[4] = (__bf16)b.x; pk[5] = (__bf16)b.y; pk[6] = (__bf16)b.z; pk[7] = (__bf16)b.w;
        *(bf16x8*)(dst + off) = pk;
        return;
    }
    int b = blockIdx.x >> 3, g = blockIdx.x & 7;
    const float4* x4 = (const float4*)(x + ((size_t)b * CH + g * GSZ) * NN);
    float s = 0.f, ss = 0.f;
    #pragma unroll
    for (int i = 0; i < 32; ++i) {
        float4 v = x4[tid + i * 256];
        s  += v.x + v.y + v.z + v.w;
        ss += v.x * v.x + v.y * v.y + v.z * v.z + v.w * v.w;
    }
    #pragma unroll
    for (int off = 1; off < 64; off <<= 1) {
        s  += __shfl_xor(s, off);
        ss += __shfl_xor(ss, off);
    }
    __shared__ float red[8];
    int wave = tid >> 6, lane = tid & 63;
    if (lane == 0) { red[wave] = s; red[4 + wave] = ss; }
    __syncthreads();
    if (tid == 0) {
        float ts  = red[0] + red[1] + red[2] + red[3];
        float tss = red[4] + red[5] + red[6] + red[7];
        float mu  = ts * (1.f / GELEMS);
        float var = tss * (1.f / GELEMS) - mu * mu;
        stats[blockIdx.x * 2] = mu;
        stats[blockIdx.x * 2 + 1] = rsqrtf(var + 1e-5f);
    }
}

// ---- GN apply + transpose: block=(n-tile 64, b). x[b][c][n] -> hT[b][n][c] bf16 ----
__global__ __launch_bounds__(256) void gn_apply_kernel(
    const float* __restrict__ x, const float* __restrict__ w,
    const float* __restrict__ bb, const float* __restrict__ stats,
    unsigned short* __restrict__ hT)
{
    __shared__ float Ts[64][68];
    __shared__ float wcp[256], bcp[256];
    const int b = blockIdx.y, n0 = blockIdx.x * 64;
    const int tid = threadIdx.x;
    {
        int c = tid, g = c >> 5;
        float mu = stats[(b * 8 + g) * 2], rs = stats[(b * 8 + g) * 2 + 1];
        float wc = w[c] * rs;
        wcp[c] = wc; bcp[c] = bb[c] - mu * wc;
    }
    __syncthreads();
    const float* xb = x + (size_t)b * CH * NN;
    const int c_l = tid >> 2, nq = tid & 3;
    const int n_l = tid >> 2, cq = tid & 3;
    for (int cb = 0; cb < 4; ++cb) {
        #pragma unroll
        for (int i = 0; i < 4; ++i)
            *(float4*)&Ts[c_l][nq * 4 + i * 16] =
                *(const float4*)(xb + (size_t)(cb * 64 + c_l) * NN + n0 + nq * 4 + i * 16);
        __syncthreads();
        #pragma unroll
        for (int s = 0; s < 2; ++s) {
            int cbase = cq * 16 + s * 8;
            bf16x8 pk;
            #pragma unroll
            for (int j = 0; j < 8; ++j) {
                int c = cb * 64 + cbase + j;
                pk[j] = (__bf16)(Ts[cbase + j][n_l] * wcp[c] + bcp[c]);
            }
            *(bf16x8*)(hT + ((size_t)b * NN + n0 + n_l) * CH + cb * 64 + cbase) = pk;
        }
        __syncthreads();
    }
}

// ---- GEMM (R6 64x64 shape + coalesced LDS-bounce epilogue) ----
// KIND 0: qkv. y<8 -> q/k: D[o][n] packs along o -> Cs[n][o] -> 128B row stores
//                  y>=8 -> v: D[n][o] packs along n -> Cs[c][n] -> 128B row stores
// KIND 1: proj. D[o][n] -> fp32 out + bias + residual (direct).
template <int KIND>
__global__ __launch_bounds__(256) void gemm_kernel(
    const unsigned short* __restrict__ AT,   // [b][1024][256] bf16
    const unsigned short* __restrict__ Wb,   // [Mtot][256] bf16
    const float* __restrict__ bias,
    unsigned short* __restrict__ outT, unsigned short* __restrict__ outV,
    const float* __restrict__ res, float* __restrict__ out)
{
    __shared__ __align__(16) unsigned short Ws[64][136];
    __shared__ __align__(16) unsigned short Hs[64][136];
    const int b = blockIdx.z, o0 = blockIdx.y * 64, n0 = blockIdx.x * 64;
    const int tid = threadIdx.x;
    const int lane = tid & 63, wv = tid >> 6;
    const int l = lane & 15, quad = lane >> 4;
    const int iw = wv & 1, jw = wv >> 1;
    const bool qk_mode = (KIND == 0) && (blockIdx.y < 8);
    const bool v_mode  = (KIND == 0) && (blockIdx.y >= 8);
    const int r4 = tid >> 2, c4 = tid & 3;

    f32x4 acc[2][2] = {};
    for (int st = 0; st < 2; ++st) {
        const int cc0 = st * 128;
        #pragma unroll
        for (int i = 0; i < 4; ++i) {
            int ch = c4 + i * 4;
            *(bf16x8*)&Ws[r4][ch * 8] =
                *(const bf16x8*)(Wb + (size_t)(o0 + r4) * CH + cc0 + ch * 8);
            *(bf16x8*)&Hs[r4][ch * 8] =
                *(const bf16x8*)(AT + ((size_t)b * NN + n0 + r4) * CH + cc0 + ch * 8);
        }
        __syncthreads();
        #pragma unroll
        for (int kt = 0; kt < 4; ++kt) {
            bf16x8 af[2], bf[2];
            #pragma unroll
            for (int i = 0; i < 2; ++i)
                af[i] = *(const bf16x8*)&Hs[iw * 32 + i * 16 + l][kt * 32 + quad * 8];
            #pragma unroll
            for (int j = 0; j < 2; ++j)
                bf[j] = *(const bf16x8*)&Ws[jw * 32 + j * 16 + l][kt * 32 + quad * 8];
            #pragma unroll
            for (int i = 0; i < 2; ++i)
                #pragma unroll
                for (int j = 0; j < 2; ++j)
                    acc[i][j] = v_mode ? MFMA(af[i], bf[j], acc[i][j])    // D[n][o]
                                       : MFMA(bf[j], af[i], acc[i][j]);   // D[o][n]
        }
        __syncthreads();
    }

    unsigned short* Cs = (unsigned short*)Ws;    // 64 x 72 bounce tile (alias, post-barrier)
    if (qk_mode) {
        // D[o][n]: row o = jw*32+j*16+quad*4+r, col n = iw*32+i*16+l. Pack along o.
        #pragma unroll
        for (int i = 0; i < 2; ++i)
            #pragma unroll
            for (int j = 0; j < 2; ++j) {
                int o_p = jw * 32 + j * 16 + quad * 4;
                int n_l = iw * 32 + i * 16 + l;
                bf16x4 pk;
                #pragma unroll
                for (int r = 0; r < 4; ++r)
                    pk[r] = (__bf16)(acc[i][j][r] + bias[o0 + o_p + r]);
                *(bf16x4*)&Cs[n_l * 72 + o_p] = pk;
            }
        __syncthreads();
        int rr = tid >> 2, ch = tid & 3;
        bf16x8 a0 = *(const bf16x8*)&Cs[rr * 72 + ch * 16];
        bf16x8 a1 = *(const bf16x8*)&Cs[rr * 72 + ch * 16 + 8];
        unsigned short* dst = outT + ((size_t)b * NN + n0 + rr) * 512 + o0 + ch * 16;
        *(bf16x8*)dst = a0;
        *(bf16x8*)(dst + 8) = a1;
    } else if (v_mode) {
        // D[n][o]: row n = iw*32+i*16+quad*4+r, col o = jw*32+j*16+l. Pack along n.
        #pragma unroll
        for (int i = 0; i < 2; ++i)
            #pragma unroll
            for (int j = 0; j < 2; ++j) {
                int n_p = iw * 32 + i * 16 + quad * 4;
                int o_l = jw * 32 + j * 16 + l;
                float bs = bias[o0 + o_l];
                f16x4 pk;
                #pragma unroll
                for (int r = 0; r < 4; ++r)
                    pk[r] = (_Float16)(acc[i][j][r] + bs);
                *(f16x4*)&Cs[o_l * 72 + n_p] = pk;
            }
        __syncthreads();
        int rr = tid >> 2, ch = tid & 3;     // rr = o index (c row of vbuf)
        bf16x8 a0 = *(const bf16x8*)&Cs[rr * 72 + ch * 16];   // raw 16B movers
        bf16x8 a1 = *(const bf16x8*)&Cs[rr * 72 + ch * 16 + 8];
        unsigned short* dst = outV + ((size_t)b * CH + (o0 + rr - 512)) * NN + n0 + ch * 16;
        *(bf16x8*)dst = a0;
        *(bf16x8*)(dst + 8) = a1;
    } else {
        // proj: D[o][n] direct fp32 + bias + residual
        #pragma unroll
        for (int i = 0; i < 2; ++i)
            #pragma unroll
            for (int j = 0; j < 2; ++j) {
                int o = o0 + jw * 32 + j * 16 + quad * 4;
                int n = n0 + iw * 32 + i * 16 + l;
                #pragma unroll
                for (int r = 0; r < 4; ++r) {
                    size_t idx = ((size_t)b * CH + o + r) * NN + n;
                    out[idx] = acc[i][j][r] + bias[o + r] + res[idx];
                }
            }
    }
}

// ---- Flash attention v4 (R6-proven): LDS dbuf K/V swizzled, P in registers ----
__global__ __launch_bounds__(256, 3) void attn_kernel(
    const unsigned short* __restrict__ qkvT,   // [b][n][512] bf16 (q 0..255, k 256..511)
    const unsigned short* __restrict__ vbuf,   // [b][256][1024] f16
    unsigned short* __restrict__ ctxT)         // [b][n][256] bf16
{
    __shared__ __align__(16) unsigned short KV[2][8192];
    __shared__ float Lred[2][32];
    const int id = blockIdx.x;
    const int bh = id & 63, nt = id >> 6;
    const int b = bh >> 2, hh = bh & 3;
    const int n0 = nt * 64;
    const int tid = threadIdx.x;
    const int lane = tid & 63, w = tid >> 6;
    const int l = lane & 15, quad = lane >> 4;
    const int qx = w & 1, ky = w >> 1;
    const float KL2E = 0.125f * 1.44269504f;
    const int r4 = tid >> 2, c4 = tid & 3;

    bf16x8 qf[2][2];
    {
        const unsigned short* qp = qkvT + ((size_t)b * NN + n0 + 32 * qx + l) * 512 + hh * 64;
        #pragma unroll
        for (int ns = 0; ns < 2; ++ns)
            #pragma unroll
            for (int kt = 0; kt < 2; ++kt)
                qf[ns][kt] = *(const bf16x8*)(qp + (size_t)ns * 16 * 512 + kt * 32 + quad * 8);
    }

    const unsigned short* gk = qkvT + ((size_t)b * NN + r4) * 512 + 256 + hh * 64;
    const unsigned short* gv = vbuf + ((size_t)b * CH + hh * 64 + r4) * NN;
    const int p0 = (c4 ^ (r4 & 7)) * 8, p1 = ((c4 + 4) ^ (r4 & 7)) * 8;

    bf16x8 kpre0, kpre1, vpre0, vpre1;
    kpre0 = *(const bf16x8*)(gk + c4 * 8);
    kpre1 = *(const bf16x8*)(gk + (c4 + 4) * 8);
    vpre0 = *(const bf16x8*)(gv + c4 * 8);
    vpre1 = *(const bf16x8*)(gv + (c4 + 4) * 8);
    *(bf16x8*)&KV[0][r4 * 64 + p0] = kpre0;
    *(bf16x8*)&KV[0][r4 * 64 + p1] = kpre1;
    *(bf16x8*)&KV[0][4096 + r4 * 64 + p0] = vpre0;
    *(bf16x8*)&KV[0][4096 + r4 * 64 + p1] = vpre1;
    __syncthreads();

    float l_w[2] = {0.f, 0.f};
    f32x4 oacc[2][4] = {};

    for (int mt = 0; mt < 16; ++mt) {
        const int cur = mt & 1;
        if (mt < 15) {
            const unsigned short* gk1 = gk + (size_t)(mt + 1) * 64 * 512;
            const unsigned short* gv1 = gv + (mt + 1) * 64;
            kpre0 = *(const bf16x8*)(gk1 + c4 * 8);
            kpre1 = *(const bf16x8*)(gk1 + (c4 + 4) * 8);
            vpre0 = *(const bf16x8*)(gv1 + c4 * 8);
            vpre1 = *(const bf16x8*)(gv1 + (c4 + 4) * 8);
        }

        bf16x8 kf[2][2];
        #pragma unroll
        for (int mt2 = 0; mt2 < 2; ++mt2)
            #pragma unroll
            for (int kt = 0; kt < 2; ++kt)
                kf[mt2][kt] = *(const bf16x8*)
                    &KV[cur][(32 * ky + 16 * mt2 + l) * 64 + (((kt * 4 + quad) ^ (l & 7)) * 8)];

        f32x4 sacc[2][2] = {};
        #pragma unroll
        for (int kt = 0; kt < 2; ++kt)
            #pragma unroll
            for (int mt2 = 0; mt2 < 2; ++mt2)
                #pragma unroll
                for (int ns = 0; ns < 2; ++ns)
                    sacc[mt2][ns] = MFMA(kf[mt2][kt], qf[ns][kt], sacc[mt2][ns]);

        f16x4 pf[2][2];
        #pragma unroll
        for (int mt2 = 0; mt2 < 2; ++mt2)
            #pragma unroll
            for (int ns = 0; ns < 2; ++ns)
                #pragma unroll
                for (int r = 0; r < 4; ++r) {
                    float p = exp2f(sacc[mt2][ns][r] * KL2E);
                    l_w[ns] += p;
                    pf[mt2][ns][r] = (_Float16)p;
                }

        #pragma unroll
        for (int mt2 = 0; mt2 < 2; ++mt2) {
            const int q8 = 4 * ky + 2 * mt2 + (quad >> 1);
            const int vo = ((q8 ^ (l & 7)) * 8) + (quad & 1) * 4;
            #pragma unroll
            for (int ct = 0; ct < 4; ++ct) {
                f16x4 va = *(const f16x4*)&KV[cur][4096 + (16 * ct + l) * 64 + vo];
                #pragma unroll
                for (int ns = 0; ns < 2; ++ns)
                    oacc[ns][ct] = MFMA16(va, pf[mt2][ns], oacc[ns][ct]);
            }
        }

        if (mt < 15) {
            const int nxt = cur ^ 1;
            *(bf16x8*)&KV[nxt][r4 * 64 + p0] = kpre0;
            *(bf16x8*)&KV[nxt][r4 * 64 + p1] = kpre1;
            *(bf16x8*)&KV[nxt][4096 + r4 * 64 + p0] = vpre0;
            *(bf16x8*)&KV[nxt][4096 + r4 * 64 + p1] = vpre1;
            __syncthreads();
        }
    }

    #pragma unroll
    for (int ns = 0; ns < 2; ++ns) {
        l_w[ns] += __shfl_xor(l_w[ns], 16);
        l_w[ns] += __shfl_xor(l_w[ns], 32);
    }
    float* Ored = (float*)&KV[0][0];
    if (ky == 1) {
        #pragma unroll
        for (int ns = 0; ns < 2; ++ns) {
            if (quad == 0) Lred[qx][ns * 16 + l] = l_w[ns];
            #pragma unroll
            for (int ct = 0; ct < 4; ++ct)
                #pragma unroll
                for (int r = 0; r < 4; ++r)
                    Ored[qx * 2048 + (16 * ct + quad * 4 + r) * 32 + ns * 16 + l] =
                        oacc[ns][ct][r];
        }
    }
    __syncthreads();
    if (ky == 0) {
        unsigned short* cb = ctxT + ((size_t)b * NN + n0 + 32 * qx) * CH + hh * 64;
        #pragma unroll
        for (int ns = 0; ns < 2; ++ns) {
            float inv = 1.f / (l_w[ns] + Lred[qx][ns * 16 + l]);
            #pragma unroll
            for (int ct = 0; ct < 4; ++ct) {
                bf16x4 pk;
                #pragma unroll
                for (int r = 0; r < 4; ++r)
                    pk[r] = (__bf16)((oacc[ns][ct][r] +
                             Ored[qx * 2048 + (16 * ct + quad * 4 + r) * 32 + ns * 16 + l]) * inv);
                *(bf16x4*)(cb + (size_t)(ns * 16 + l) * CH + 16 * ct + quad * 4) = pk;
            }
        }
    }
}

extern "C" void kernel_launch(void* const* d_in, const int* in_sizes, int n_in,
                              void* d_out, int out_size, void* d_ws, size_t ws_size,
                              hipStream_t stream)
{
    const float* x      = (const float*)d_in[0];
    const float* norm_w = (const float*)d_in[1];
    const float* norm_b = (const float*)d_in[2];
    const float* qkv_w  = (const float*)d_in[3];
    const float* qkv_b  = (const float*)d_in[4];
    const float* proj_w = (const float*)d_in[5];
    const float* proj_b = (const float*)d_in[6];
    float* out = (float*)d_out;

    unsigned short* hT   = (unsigned short*)d_ws;
    unsigned short* qkvT = hT   + (size_t)BATCH * NN * CH;
    unsigned short* vbuf = qkvT + (size_t)BATCH * NN * 512;
    unsigned short* ctxT = vbuf + (size_t)BATCH * CH * NN;
    unsigned short* wq   = ctxT + (size_t)BATCH * NN * CH;
    unsigned short* wp   = wq + (size_t)768 * CH;
    float* stats         = (float*)(wp + (size_t)CH * CH);

    prep_kernel<<<dim3(256), 256, 0, stream>>>(x, qkv_w, proj_w, stats, wq, wp);
    gn_apply_kernel<<<dim3(16, BATCH), 256, 0, stream>>>(x, norm_w, norm_b, stats, hT);
    gemm_kernel<0><<<dim3(NN / 64, 12, BATCH), 256, 0, stream>>>(
        hT, wq, qkv_b, qkvT, vbuf, nullptr, nullptr);
    attn_kernel<<<dim3(1024), 256, 0, stream>>>(qkvT, vbuf, ctxT);
    gemm_kernel<1><<<dim3(NN / 64, 4, BATCH), 256, 0, stream>>>(
        ctxT, wp, proj_b, nullptr, nullptr, x, out);
}

// Round 9
// 145.850 us; speedup vs baseline: 1.1379x; 1.0054x over previous
//
#include <hip/hip_runtime.h>
#include <math.h>

#define BATCH 16
#define CH 256
#define NG 8
#define NH 4
#define HD 64
#define NN 1024
#define GSZ 32
#define GELEMS (GSZ * NN)

typedef __attribute__((ext_vector_type(8))) __bf16 bf16x8;
typedef __attribute__((ext_vector_type(4))) __bf16 bf16x4;
typedef __attribute__((ext_vector_type(4))) _Float16 f16x4;
typedef __attribute__((ext_vector_type(4))) float f32x4;

__device__ __forceinline__ unsigned short f2b(float f) {
    union { __bf16 h; unsigned short u; } c; c.h = (__bf16)f; return c.u;
}
__device__ __forceinline__ unsigned short f2h(float f) {
    union { _Float16 h; unsigned short u; } c; c.h = (_Float16)f; return c.u;
}

#define MFMA(a, b, c) __builtin_amdgcn_mfma_f32_16x16x32_bf16(a, b, c, 0, 0, 0)
#define MFMA16(a, b, c) __builtin_amdgcn_mfma_f32_16x16x16f16(a, b, c, 0, 0, 0)

// ---- fused GN (stats + apply + transpose) & W-convert ----
// blocks 0..127: (b,g) -> stats over 32ch x 1024n slice, then L2-hot re-read,
//                normalize, transpose via LDS, write hT[b][n][g*32..+32] bf16.
// blocks 128..255: W fp32->bf16 (qkv_w then proj_w).
__global__ __launch_bounds__(256) void gnw_kernel(
    const float* __restrict__ x, const float* __restrict__ w,
    const float* __restrict__ bb, const float* __restrict__ qkv_w,
    const float* __restrict__ proj_w, unsigned short* __restrict__ hT,
    unsigned short* __restrict__ wq, unsigned short* __restrict__ wp)
{
    int tid = threadIdx.x;
    if (blockIdx.x >= 128) {
        int t = (blockIdx.x - 128) * 256 + tid;
        const float* src; unsigned short* dst; size_t off;
        if (t < 24576) { src = qkv_w; dst = wq; off = (size_t)t * 8; }
        else           { src = proj_w; dst = wp; off = (size_t)(t - 24576) * 8; }
        const float4* s4 = (const float4*)(src + off);
        float4 a = s4[0], b = s4[1];
        bf16x8 pk;
        pk[0] = (__bf16)a.x; pk[1] = (__bf16)a.y; pk[2] = (__bf16)a.z; pk[3] = (__bf16)a.w;
        pk[4] = (__bf16)b.x; pk[5] = (__bf16)b.y; pk[6] = (__bf16)b.z; pk[7] = (__bf16)b.w;
        *(bf16x8*)(dst + off) = pk;
        return;
    }
    const int b = blockIdx.x >> 3, g = blockIdx.x & 7;
    const float* xb = x + ((size_t)b * CH + g * GSZ) * NN;
    const float4* x4 = (const float4*)xb;

    // ---- phase A: stats ----
    float s = 0.f, ss = 0.f;
    #pragma unroll
    for (int i = 0; i < 32; ++i) {
        float4 v = x4[tid + i * 256];
        s  += v.x + v.y + v.z + v.w;
        ss += v.x * v.x + v.y * v.y + v.z * v.z + v.w * v.w;
    }
    #pragma unroll
    for (int off = 1; off < 64; off <<= 1) {
        s  += __shfl_xor(s, off);
        ss += __shfl_xor(ss, off);
    }
    __shared__ float red[8];
    int wave = tid >> 6, lane = tid & 63;
    if (lane == 0) { red[wave] = s; red[4 + wave] = ss; }
    __syncthreads();
    if (tid == 0) {
        float ts  = red[0] + red[1] + red[2] + red[3];
        float tss = red[4] + red[5] + red[6] + red[7];
        float mu  = ts * (1.f / GELEMS);
        float var = tss * (1.f / GELEMS) - mu * mu;
        red[0] = mu; red[1] = rsqrtf(var + 1e-5f);
    }
    __syncthreads();
    const float mu = red[0], rs = red[1];

    // ---- phase B: apply + transpose (x slice is L2-hot from phase A) ----
    const int co = tid & 3;                   // channel octet for writes
    float wcv[8], bcv[8];
    #pragma unroll
    for (int j = 0; j < 8; ++j) {
        int c = g * GSZ + co * 8 + j;
        wcv[j] = w[c] * rs;
        bcv[j] = bb[c] - mu * wcv[j];
    }
    __shared__ float Ts[32][66];              // stride 66: float2-aligned, 2-way banks
    const int cs = tid >> 3, q = tid & 7;     // staging: row c, 8-n chunk
    const int n_l = tid >> 2;                 // write: row n within tile
    for (int nt = 0; nt < 16; ++nt) {
        const float2* src = (const float2*)(xb + (size_t)cs * NN + nt * 64 + q * 8);
        #pragma unroll
        for (int t = 0; t < 4; ++t)
            *(float2*)&Ts[cs][q * 8 + t * 2] = src[t];
        __syncthreads();
        bf16x8 pk;
        #pragma unroll
        for (int j = 0; j < 8; ++j)
            pk[j] = (__bf16)(Ts[co * 8 + j][n_l] * wcv[j] + bcv[j]);
        *(bf16x8*)(hT + ((size_t)b * NN + nt * 64 + n_l) * CH + g * GSZ + co * 8) = pk;
        __syncthreads();
    }
}

// ---- GEMM (R8-proven): 64x64 tile, 2x2 wave, coalesced LDS-bounce epilogue ----
template <int KIND>
__global__ __launch_bounds__(256) void gemm_kernel(
    const unsigned short* __restrict__ AT,   // [b][1024][256] bf16
    const unsigned short* __restrict__ Wb,   // [Mtot][256] bf16
    const float* __restrict__ bias,
    unsigned short* __restrict__ outT, unsigned short* __restrict__ outV,
    const float* __restrict__ res, float* __restrict__ out)
{
    __shared__ __align__(16) unsigned short Ws[64][136];
    __shared__ __align__(16) unsigned short Hs[64][136];
    const int b = blockIdx.z, o0 = blockIdx.y * 64, n0 = blockIdx.x * 64;
    const int tid = threadIdx.x;
    const int lane = tid & 63, wv = tid >> 6;
    const int l = lane & 15, quad = lane >> 4;
    const int iw = wv & 1, jw = wv >> 1;
    const bool qk_mode = (KIND == 0) && (blockIdx.y < 8);
    const bool v_mode  = (KIND == 0) && (blockIdx.y >= 8);
    const int r4 = tid >> 2, c4 = tid & 3;

    f32x4 acc[2][2] = {};
    for (int st = 0; st < 2; ++st) {
        const int cc0 = st * 128;
        #pragma unroll
        for (int i = 0; i < 4; ++i) {
            int ch = c4 + i * 4;
            *(bf16x8*)&Ws[r4][ch * 8] =
                *(const bf16x8*)(Wb + (size_t)(o0 + r4) * CH + cc0 + ch * 8);
            *(bf16x8*)&Hs[r4][ch * 8] =
                *(const bf16x8*)(AT + ((size_t)b * NN + n0 + r4) * CH + cc0 + ch * 8);
        }
        __syncthreads();
        #pragma unroll
        for (int kt = 0; kt < 4; ++kt) {
            bf16x8 af[2], bf[2];
            #pragma unroll
            for (int i = 0; i < 2; ++i)
                af[i] = *(const bf16x8*)&Hs[iw * 32 + i * 16 + l][kt * 32 + quad * 8];
            #pragma unroll
            for (int j = 0; j < 2; ++j)
                bf[j] = *(const bf16x8*)&Ws[jw * 32 + j * 16 + l][kt * 32 + quad * 8];
            #pragma unroll
            for (int i = 0; i < 2; ++i)
                #pragma unroll
                for (int j = 0; j < 2; ++j)
                    acc[i][j] = v_mode ? MFMA(af[i], bf[j], acc[i][j])    // D[n][o]
                                       : MFMA(bf[j], af[i], acc[i][j]);   // D[o][n]
        }
        __syncthreads();
    }

    unsigned short* Cs = (unsigned short*)Ws;
    if (qk_mode) {
        #pragma unroll
        for (int i = 0; i < 2; ++i)
            #pragma unroll
            for (int j = 0; j < 2; ++j) {
                int o_p = jw * 32 + j * 16 + quad * 4;
                int n_l = iw * 32 + i * 16 + l;
                bf16x4 pk;
                #pragma unroll
                for (int r = 0; r < 4; ++r)
                    pk[r] = (__bf16)(acc[i][j][r] + bias[o0 + o_p + r]);
                *(bf16x4*)&Cs[n_l * 72 + o_p] = pk;
            }
        __syncthreads();
        int rr = tid >> 2, ch = tid & 3;
        bf16x8 a0 = *(const bf16x8*)&Cs[rr * 72 + ch * 16];
        bf16x8 a1 = *(const bf16x8*)&Cs[rr * 72 + ch * 16 + 8];
        unsigned short* dst = outT + ((size_t)b * NN + n0 + rr) * 512 + o0 + ch * 16;
        *(bf16x8*)dst = a0;
        *(bf16x8*)(dst + 8) = a1;
    } else if (v_mode) {
        #pragma unroll
        for (int i = 0; i < 2; ++i)
            #pragma unroll
            for (int j = 0; j < 2; ++j) {
                int n_p = iw * 32 + i * 16 + quad * 4;
                int o_l = jw * 32 + j * 16 + l;
                float bs = bias[o0 + o_l];
                f16x4 pk;
                #pragma unroll
                for (int r = 0; r < 4; ++r)
                    pk[r] = (_Float16)(acc[i][j][r] + bs);
                *(f16x4*)&Cs[o_l * 72 + n_p] = pk;
            }
        __syncthreads();
        int rr = tid >> 2, ch = tid & 3;
        bf16x8 a0 = *(const bf16x8*)&Cs[rr * 72 + ch * 16];
        bf16x8 a1 = *(const bf16x8*)&Cs[rr * 72 + ch * 16 + 8];
        unsigned short* dst = outV + ((size_t)b * CH + (o0 + rr - 512)) * NN + n0 + ch * 16;
        *(bf16x8*)dst = a0;
        *(bf16x8*)(dst + 8) = a1;
    } else {
        #pragma unroll
        for (int i = 0; i < 2; ++i)
            #pragma unroll
            for (int j = 0; j < 2; ++j) {
                int o = o0 + jw * 32 + j * 16 + quad * 4;
                int n = n0 + iw * 32 + i * 16 + l;
                #pragma unroll
                for (int r = 0; r < 4; ++r) {
                    size_t idx = ((size_t)b * CH + o + r) * NN + n;
                    out[idx] = acc[i][j][r] + bias[o + r] + res[idx];
                }
            }
    }
}

// ---- Flash attention v4 (R6-proven), now 4 blocks/CU ----
__global__ __launch_bounds__(256, 4) void attn_kernel(
    const unsigned short* __restrict__ qkvT,   // [b][n][512] bf16 (q 0..255, k 256..511)
    const unsigned short* __restrict__ vbuf,   // [b][256][1024] f16
    unsigned short* __restrict__ ctxT)         // [b][n][256] bf16
{
    __shared__ __align__(16) unsigned short KV[2][8192];
    __shared__ float Lred[2][32];
    const int id = blockIdx.x;
    const int bh = id & 63, nt = id >> 6;
    const int b = bh >> 2, hh = bh & 3;
    const int n0 = nt * 64;
    const int tid = threadIdx.x;
    const int lane = tid & 63, w = tid >> 6;
    const int l = lane & 15, quad = lane >> 4;
    const int qx = w & 1, ky = w >> 1;
    const float KL2E = 0.125f * 1.44269504f;
    const int r4 = tid >> 2, c4 = tid & 3;

    bf16x8 qf[2][2];
    {
        const unsigned short* qp = qkvT + ((size_t)b * NN + n0 + 32 * qx + l) * 512 + hh * 64;
        #pragma unroll
        for (int ns = 0; ns < 2; ++ns)
            #pragma unroll
            for (int kt = 0; kt < 2; ++kt)
                qf[ns][kt] = *(const bf16x8*)(qp + (size_t)ns * 16 * 512 + kt * 32 + quad * 8);
    }

    const unsigned short* gk = qkvT + ((size_t)b * NN + r4) * 512 + 256 + hh * 64;
    const unsigned short* gv = vbuf + ((size_t)b * CH + hh * 64 + r4) * NN;
    const int p0 = (c4 ^ (r4 & 7)) * 8, p1 = ((c4 + 4) ^ (r4 & 7)) * 8;

    bf16x8 kpre0, kpre1, vpre0, vpre1;
    kpre0 = *(const bf16x8*)(gk + c4 * 8);
    kpre1 = *(const bf16x8*)(gk + (c4 + 4) * 8);
    vpre0 = *(const bf16x8*)(gv + c4 * 8);
    vpre1 = *(const bf16x8*)(gv + (c4 + 4) * 8);
    *(bf16x8*)&KV[0][r4 * 64 + p0] = kpre0;
    *(bf16x8*)&KV[0][r4 * 64 + p1] = kpre1;
    *(bf16x8*)&KV[0][4096 + r4 * 64 + p0] = vpre0;
    *(bf16x8*)&KV[0][4096 + r4 * 64 + p1] = vpre1;
    __syncthreads();

    float l_w[2] = {0.f, 0.f};
    f32x4 oacc[2][4] = {};

    for (int mt = 0; mt < 16; ++mt) {
        const int cur = mt & 1;
        if (mt < 15) {
            const unsigned short* gk1 = gk + (size_t)(mt + 1) * 64 * 512;
            const unsigned short* gv1 = gv + (mt + 1) * 64;
            kpre0 = *(const bf16x8*)(gk1 + c4 * 8);
            kpre1 = *(const bf16x8*)(gk1 + (c4 + 4) * 8);
            vpre0 = *(const bf16x8*)(gv1 + c4 * 8);
            vpre1 = *(const bf16x8*)(gv1 + (c4 + 4) * 8);
        }

        bf16x8 kf[2][2];
        #pragma unroll
        for (int mt2 = 0; mt2 < 2; ++mt2)
            #pragma unroll
            for (int kt = 0; kt < 2; ++kt)
                kf[mt2][kt] = *(const bf16x8*)
                    &KV[cur][(32 * ky + 16 * mt2 + l) * 64 + (((kt * 4 + quad) ^ (l & 7)) * 8)];

        f32x4 sacc[2][2] = {};
        #pragma unroll
        for (int kt = 0; kt < 2; ++kt)
            #pragma unroll
            for (int mt2 = 0; mt2 < 2; ++mt2)
                #pragma unroll
                for (int ns = 0; ns < 2; ++ns)
                    sacc[mt2][ns] = MFMA(kf[mt2][kt], qf[ns][kt], sacc[mt2][ns]);

        f16x4 pf[2][2];
        #pragma unroll
        for (int mt2 = 0; mt2 < 2; ++mt2)
            #pragma unroll
            for (int ns = 0; ns < 2; ++ns)
                #pragma unroll
                for (int r = 0; r < 4; ++r) {
                    float p = exp2f(sacc[mt2][ns][r] * KL2E);
                    l_w[ns] += p;
                    pf[mt2][ns][r] = (_Float16)p;
                }

        #pragma unroll
        for (int mt2 = 0; mt2 < 2; ++mt2) {
            const int q8 = 4 * ky + 2 * mt2 + (quad >> 1);
            const int vo = ((q8 ^ (l & 7)) * 8) + (quad & 1) * 4;
            #pragma unroll
            for (int ct = 0; ct < 4; ++ct) {
                f16x4 va = *(const f16x4*)&KV[cur][4096 + (16 * ct + l) * 64 + vo];
                #pragma unroll
                for (int ns = 0; ns < 2; ++ns)
                    oacc[ns][ct] = MFMA16(va, pf[mt2][ns], oacc[ns][ct]);
            }
        }

        if (mt < 15) {
            const int nxt = cur ^ 1;
            *(bf16x8*)&KV[nxt][r4 * 64 + p0] = kpre0;
            *(bf16x8*)&KV[nxt][r4 * 64 + p1] = kpre1;
            *(bf16x8*)&KV[nxt][4096 + r4 * 64 + p0] = vpre0;
            *(bf16x8*)&KV[nxt][4096 + r4 * 64 + p1] = vpre1;
            __syncthreads();
        }
    }

    #pragma unroll
    for (int ns = 0; ns < 2; ++ns) {
        l_w[ns] += __shfl_xor(l_w[ns], 16);
        l_w[ns] += __shfl_xor(l_w[ns], 32);
    }
    float* Ored = (float*)&KV[0][0];
    if (ky == 1) {
        #pragma unroll
        for (int ns = 0; ns < 2; ++ns) {
            if (quad == 0) Lred[qx][ns * 16 + l] = l_w[ns];
            #pragma unroll
            for (int ct = 0; ct < 4; ++ct)
                #pragma unroll
                for (int r = 0; r < 4; ++r)
                    Ored[qx * 2048 + (16 * ct + quad * 4 + r) * 32 + ns * 16 + l] =
                        oacc[ns][ct][r];
        }
    }
    __syncthreads();
    if (ky == 0) {
        unsigned short* cb = ctxT + ((size_t)b * NN + n0 + 32 * qx) * CH + hh * 64;
        #pragma unroll
        for (int ns = 0; ns < 2; ++ns) {
            float inv = 1.f / (l_w[ns] + Lred[qx][ns * 16 + l]);
            #pragma unroll
            for (int ct = 0; ct < 4; ++ct) {
                bf16x4 pk;
                #pragma unroll
                for (int r = 0; r < 4; ++r)
                    pk[r] = (__bf16)((oacc[ns][ct][r] +
                             Ored[qx * 2048 + (16 * ct + quad * 4 + r) * 32 + ns * 16 + l]) * inv);
                *(bf16x4*)(cb + (size_t)(ns * 16 + l) * CH + 16 * ct + quad * 4) = pk;
            }
        }
    }
}

extern "C" void kernel_launch(void* const* d_in, const int* in_sizes, int n_in,
                              void* d_out, int out_size, void* d_ws, size_t ws_size,
                              hipStream_t stream)
{
    const float* x      = (const float*)d_in[0];
    const float* norm_w = (const float*)d_in[1];
    const float* norm_b = (const float*)d_in[2];
    const float* qkv_w  = (const float*)d_in[3];
    const float* qkv_b  = (const float*)d_in[4];
    const float* proj_w = (const float*)d_in[5];
    const float* proj_b = (const float*)d_in[6];
    float* out = (float*)d_out;

    unsigned short* hT   = (unsigned short*)d_ws;
    unsigned short* qkvT = hT   + (size_t)BATCH * NN * CH;
    unsigned short* vbuf = qkvT + (size_t)BATCH * NN * 512;
    unsigned short* ctxT = vbuf + (size_t)BATCH * CH * NN;
    unsigned short* wq   = ctxT + (size_t)BATCH * NN * CH;
    unsigned short* wp   = wq + (size_t)768 * CH;

    gnw_kernel<<<dim3(256), 256, 0, stream>>>(x, norm_w, norm_b, qkv_w, proj_w, hT, wq, wp);
    gemm_kernel<0><<<dim3(NN / 64, 12, BATCH), 256, 0, stream>>>(
        hT, wq, qkv_b, qkvT, vbuf, nullptr, nullptr);
    attn_kernel<<<dim3(1024), 256, 0, stream>>>(qkvT, vbuf, ctxT);
    gemm_kernel<1><<<dim3(NN / 64, 4, BATCH), 256, 0, stream>>>(
        ctxT, wp, proj_b, nullptr, nullptr, x, out);
}